// Round 10
// baseline (220.114 us; speedup 1.0000x reference)
//
#include <hip/hip_runtime.h>
#include <hip/hip_bf16.h>
#include <cstdint>
#include <cstddef>

// ---------------------------------------------------------------------------
// E3nnMLPNorm: only the l=1 (d=3) irrep path is nonzero.
// layer0(+colsumsq) -> [gemm(+colsumsq) -> bn+gate] x5 -> final dot
// Precision: bf16 hi+lo pairs, 3 bf16 MFMA per fragment into f32 acc.
// R10: 128x128 tile / 512 thr (halves staged bytes: 393->196 MB, R9 showed
// staging-BW-bound at ~13 TB/s) + fragment-blocked C stores (256B-contig
// per store; R9 left C as 4B-scatter @4KB stride = write-side channel
// conflicts). All operands K-blocked (R9's win). 2-deep dbuf, vmcnt(4).
// ---------------------------------------------------------------------------

typedef short    s16x8 __attribute__((ext_vector_type(8)));
typedef float    f32x4 __attribute__((ext_vector_type(4)));

#define PLANE 1048576   // 1024*1024 elements per plane

__device__ __forceinline__ unsigned short f2bf(float f) {
  unsigned u = __builtin_bit_cast(unsigned, f);
  u += 0x7FFFu + ((u >> 16) & 1u);              // round-to-nearest-even
  return (unsigned short)(u >> 16);
}
__device__ __forceinline__ float bf2f(unsigned short h) {
  return __builtin_bit_cast(float, (unsigned)h << 16);
}

// byte offset of element (row, k) in the K-blocked bf16 operand layout:
// [row>>6][k>>5][(row>>4)&3][(k>>3)&3][row&15][k&7]
__device__ __forceinline__ size_t ablk(int row, int k) {
  return ((size_t)(row >> 6) << 17) + ((size_t)(k >> 5) << 12)
       + ((size_t)((row >> 4) & 3) << 10) + ((size_t)((k >> 3) & 3) << 8)
       + ((size_t)(row & 15) << 4) + ((size_t)(k & 7) << 1);
}

// float index of C element (r, c) in the fragment-blocked layout written by
// gemm: [tM][tN][wave][m][n][j][lane], lane = kcsel*16 + rsel.
__device__ __forceinline__ size_t cblk(int r, int c) {
  const int tM = r >> 7, tN = c >> 7;
  const int rr = r & 127, cc = c & 127;
  const int wave = ((rr >> 6) << 2) | (cc >> 5);
  const int m = (rr >> 4) & 3, j = rr & 3;
  const int n = (cc >> 4) & 1;
  const int lane = (((rr >> 2) & 3) << 4) | (cc & 15);
  return (((size_t)((tM * 8 + tN) * 8 + wave)) << 11)
       + (size_t)(((((m << 1) | n) << 2) | j) << 6) + lane;
}

__device__ __forceinline__ void load_lds16(const void* g, void* l) {
  __builtin_amdgcn_global_load_lds(
      (const __attribute__((address_space(1))) unsigned int*)g,
      (__attribute__((address_space(3))) unsigned int*)l,
      16, 0, 0);
}

// ---- W[b,0] (f32 [u][v]) -> blocked bf16 hi/lo (row=v, k=u), 1/32 folded ----
__global__ void convert_w(const float* __restrict__ W,
                          unsigned short* __restrict__ Wh,
                          unsigned short* __restrict__ Wl) {
  __shared__ float t[64][65];
  const int u0 = blockIdx.x * 64, v0 = blockIdx.y * 64;
  const float* Wb = W + (size_t)blockIdx.z * 4194304;   // [5][4][1024][1024], irrep 0
  char* Whb = (char*)(Wh + (size_t)blockIdx.z * PLANE);
  char* Wlb = (char*)(Wl + (size_t)blockIdx.z * PLANE);
  const int c = threadIdx.x & 63, r4 = threadIdx.x >> 6;
#pragma unroll
  for (int i = 0; i < 16; ++i) {
    const int r = i * 4 + r4;
    t[r][c] = Wb[(size_t)(u0 + r) * 1024 + v0 + c];
  }
  __syncthreads();
#pragma unroll
  for (int i = 0; i < 16; ++i) {
    const int r = i * 4 + r4;   // local v index
    const float w = t[c][r] * 0.03125f;      // exact pow2 scale
    const unsigned short hi = f2bf(w);
    const size_t off = ablk(v0 + r, u0 + c);
    *(unsigned short*)(Whb + off) = hi;
    *(unsigned short*)(Wlb + off) = f2bf(w - bf2f(hi));
  }
}

// ---- layer0 + fused colsumsq: pre[i][b][v] (linear f32), var[v] += sum f^2 --
__global__ void layer0_fused(const float* __restrict__ x, const float* __restrict__ w1,
                             float* __restrict__ pre, float* __restrict__ var) {
  const int v = blockIdx.x * 256 + threadIdx.x;
  const int b0 = blockIdx.y * 16;
  const float a0 = w1[v], a1 = w1[1024 + v];
  const float inv = 0.70710678118654752f;
  float ssq = 0.f;
#pragma unroll 4
  for (int bb = 0; bb < 16; ++bb) {
    const int b = b0 + bb;
    const float* xb = x + b * 6;                    // x flat [B][2][3]
#pragma unroll
    for (int i = 0; i < 3; ++i) {
      const float f = (xb[i] * a0 + xb[3 + i] * a1) * inv;
      pre[(size_t)i * PLANE + (size_t)b * 1024 + v] = f;
      ssq += f * f;
    }
  }
  atomicAdd(&var[v], ssq);
}

// ---- batchnorm + norm-gated sigmoid: C (linear or blocked) -> blocked hi/lo -
// block: 16 b x 128 v; thread: b = 16bx + (tid&15), v0 = 128by + (tid>>4)*8.
template <bool BLK>
__global__ void act_kernel(const float* __restrict__ Cin, const float* __restrict__ var,
                           const float* __restrict__ bnw,
                           char* __restrict__ ah, char* __restrict__ al) {
  const int tid = threadIdx.x;
  const int b  = blockIdx.x * 16 + (tid & 15);
  const int v0 = blockIdx.y * 128 + (tid >> 4) * 8;
  float s[8];
#pragma unroll
  for (int j = 0; j < 8; ++j)
    s[j] = bnw[v0 + j] / sqrtf(var[v0 + j] * (1.0f / 3072.0f) + 1e-5f);
  float f[3][8];
#pragma unroll
  for (int i = 0; i < 3; ++i) {
    float4 p0, p1;
    if (BLK) {
      const size_t ci = cblk(i * 1024 + b, v0);     // 8 cols -> 8 consecutive floats
      p0 = *(const float4*)&Cin[ci];
      p1 = *(const float4*)&Cin[ci + 4];
    } else {
      p0 = *(const float4*)&Cin[(size_t)i * PLANE + (size_t)b * 1024 + v0];
      p1 = *(const float4*)&Cin[(size_t)i * PLANE + (size_t)b * 1024 + v0 + 4];
    }
    f[i][0] = p0.x * s[0]; f[i][1] = p0.y * s[1]; f[i][2] = p0.z * s[2]; f[i][3] = p0.w * s[3];
    f[i][4] = p1.x * s[4]; f[i][5] = p1.y * s[5]; f[i][6] = p1.z * s[6]; f[i][7] = p1.w * s[7];
  }
#pragma unroll
  for (int j = 0; j < 8; ++j) {
    const float n = sqrtf(f[0][j] * f[0][j] + f[1][j] * f[1][j] + f[2][j] * f[2][j] + 1e-8f);
    const float g = 1.0f / ((1.0f + expf(-n)) * n);   // sigmoid(n)/n
    f[0][j] *= g; f[1][j] *= g; f[2][j] *= g;
  }
#pragma unroll
  for (int i = 0; i < 3; ++i) {
    s16x8 hi, lo;
#pragma unroll
    for (int j = 0; j < 8; ++j) {
      const unsigned short h = f2bf(f[i][j]);
      hi[j] = (short)h;
      lo[j] = (short)f2bf(f[i][j] - bf2f(h));
    }
    const size_t off = ablk(i * 1024 + b, v0);
    *(s16x8*)(ah + off) = hi;
    *(s16x8*)(al + off) = lo;
  }
}

// ---- bf16-pair MFMA GEMM + fused colsumsq, 128x128 tile, 8 waves ------------
// C(frag-blocked)[3072][1024] = (Ah+Al)(Bh+Bl)^T ; var[col] += sum_rows C^2
// wave (wr=wave>>2, wc=wave&3) owns 64x32: 4x2 frags of 16x16x32.
__global__ __launch_bounds__(512, 2) void gemm_fused(
    const char* __restrict__ Ah, const char* __restrict__ Al,
    const char* __restrict__ Bh, const char* __restrict__ Bl,
    float* __restrict__ C, float* __restrict__ var) {
  // [buf 2][g 32][kc 4][rl 16][8 halves] = 64 KB; g = mat*8 + rb*4 + wq
  __shared__ unsigned short lds[2][32][4][16][8];
  const int tid = threadIdx.x;
  // XCD M-stripe: xcd owns 3 M-tiles (1.5 MB A-stripe) x all 8 N-tiles
  const int bid = blockIdx.x;
  const int xcd = bid & 7, q = bid >> 3;          // q in 0..23
  const int bm0 = (xcd * 3 + (q % 3)) * 128;
  const int bn0 = (q / 3) * 128;
  const int lane = tid & 63, wave = tid >> 6;
  const int wr = wave >> 2, wc = wave & 3;
  const int rsel = lane & 15, kcsel = lane >> 4;

  f32x4 acc[4][2] = {};

  // staging sources: wave covers 4 segments g = wave*4 + l (1KB contiguous ea.)
  const char* gsrc[4];
#pragma unroll
  for (int l = 0; l < 4; ++l) {
    const int g = wave * 4 + l;
    const int mat = g >> 3, rb = (g >> 2) & 1, wq = g & 3;
    const char* base = (mat == 0) ? Ah : (mat == 1) ? Al : (mat == 2) ? Bh : Bl;
    const int rowblk = ((mat < 2) ? (bm0 >> 6) : (bn0 >> 6)) + rb;
    gsrc[l] = base + ((size_t)rowblk << 17) + (wq << 10) + (lane << 4);
  }

  auto stage = [&](int buf, int t) {
    char* ld = (char*)lds + (buf << 15) + wave * 4096;   // wave-uniform dest
#pragma unroll
    for (int l = 0; l < 4; ++l)
      load_lds16(gsrc[l] + ((size_t)t << 12), ld + l * 1024);
  };

  const int fo = kcsel * 256 + rsel * 16;          // bytes within 1KB segment
  auto compute = [&](int buf) {
    const char* p = (const char*)lds + (buf << 15);
    s16x8 fah[4], fal[4], fbh[2], fbl[2];
#pragma unroll
    for (int m = 0; m < 4; ++m) {
      fah[m] = *(const s16x8*)(p + ((wr * 4 + m) << 10) + fo);
      fal[m] = *(const s16x8*)(p + ((8 + wr * 4 + m) << 10) + fo);
    }
#pragma unroll
    for (int n = 0; n < 2; ++n) {
      fbh[n] = *(const s16x8*)(p + ((16 + wc * 2 + n) << 10) + fo);
      fbl[n] = *(const s16x8*)(p + ((24 + wc * 2 + n) << 10) + fo);
    }
#pragma unroll
    for (int m = 0; m < 4; ++m)
#pragma unroll
      for (int n = 0; n < 2; ++n) {
        acc[m][n] = __builtin_amdgcn_mfma_f32_16x16x32_bf16(fal[m], fbh[n], acc[m][n], 0, 0, 0);
        acc[m][n] = __builtin_amdgcn_mfma_f32_16x16x32_bf16(fah[m], fbl[n], acc[m][n], 0, 0, 0);
        acc[m][n] = __builtin_amdgcn_mfma_f32_16x16x32_bf16(fah[m], fbh[n], acc[m][n], 0, 0, 0);
      }
  };

  stage(0, 0);                                     // prologue
  for (int t = 0; t < 31; ++t) {
    stage((t + 1) & 1, t + 1);                     // prefetch next K-step
    __builtin_amdgcn_sched_barrier(0);
    asm volatile("s_waitcnt vmcnt(4)" ::: "memory");  // wait stage(t) only
    __builtin_amdgcn_sched_barrier(0);
    __builtin_amdgcn_s_barrier();
    compute(t & 1);
    __builtin_amdgcn_sched_barrier(0);
    __builtin_amdgcn_s_barrier();                  // protect buf before overwrite
  }
  __builtin_amdgcn_sched_barrier(0);
  asm volatile("s_waitcnt vmcnt(0)" ::: "memory");
  __builtin_amdgcn_sched_barrier(0);
  __builtin_amdgcn_s_barrier();
  compute(1);                                      // t=31

  // epilogue: fragment-blocked C store (256B contiguous per store) + colsumsq
  const int tM = bm0 >> 7, tN = bn0 >> 7;
  float* cw = C + (((size_t)((tM * 8 + tN) * 8 + wave)) << 11) + lane;
  float csq[2] = {0.f, 0.f};
#pragma unroll
  for (int m = 0; m < 4; ++m)
#pragma unroll
    for (int n = 0; n < 2; ++n)
#pragma unroll
      for (int j = 0; j < 4; ++j) {
        const float v = acc[m][n][j];
        cw[((((m << 1) | n) << 2) | j) << 6] = v;
        csq[n] += v * v;
      }
  // reduce over kcsel (row groups): lanes rsel, +16, +32, +48
#pragma unroll
  for (int n = 0; n < 2; ++n) {
    csq[n] += __shfl_xor(csq[n], 16);
    csq[n] += __shfl_xor(csq[n], 32);
  }
  if (kcsel == 0) {
#pragma unroll
    for (int n = 0; n < 2; ++n)
      atomicAdd(&var[bn0 + wc * 32 + n * 16 + rsel], csq[n]);
  }
}

// ---- final: out[b,i] = (1/32) * sum_v act[i][b][v] * wout[v] ----------------
__global__ void final_kernel(const char* __restrict__ ah, const char* __restrict__ al,
                             const float* __restrict__ wout, float* __restrict__ out) {
  const int b = blockIdx.x, tid = threadIdx.x;
  __shared__ float red[3][4];
  float s[3] = {0.f, 0.f, 0.f};
  if (tid < 128) {
    const int v0 = tid * 8;
#pragma unroll
    for (int i = 0; i < 3; ++i) {
      const size_t off = ablk(i * 1024 + b, v0);
      const s16x8 hi = *(const s16x8*)(ah + off);
      const s16x8 lo = *(const s16x8*)(al + off);
#pragma unroll
      for (int j = 0; j < 8; ++j)
        s[i] += (bf2f((unsigned short)hi[j]) + bf2f((unsigned short)lo[j])) * wout[v0 + j];
    }
  }
#pragma unroll
  for (int i = 0; i < 3; ++i)
    for (int o = 32; o >= 1; o >>= 1) s[i] += __shfl_down(s[i], o);
  if ((tid & 63) == 0)
#pragma unroll
    for (int i = 0; i < 3; ++i) red[i][tid >> 6] = s[i];
  __syncthreads();
  if (tid < 3) {
    const float t = red[tid][0] + red[tid][1] + red[tid][2] + red[tid][3];
    out[b * 3 + tid] = t * 0.03125f;
  }
}

extern "C" void kernel_launch(void* const* d_in, const int* in_sizes, int n_in,
                              void* d_out, int out_size, void* d_ws, size_t ws_size,
                              hipStream_t stream) {
  const float* x    = (const float*)d_in[0];
  const float* w1   = (const float*)d_in[1];
  const float* W    = (const float*)d_in[2];
  const float* bnw  = (const float*)d_in[3];
  const float* wout = (const float*)d_in[4];
  float* out = (float*)d_out;

  char* ws = (char*)d_ws;
  float*          var = (float*)ws;                         // 6*1024 f32 (32 KB resv)
  float*          pre = (float*)(ws + 32768);               // C buffer, 12 MB
  char*           ah  = ws + 12615680;                      // blocked bf16 (6 MB)
  char*           al  = ws + 18907136;                      // blocked bf16 (6 MB)
  unsigned short* wh  = (unsigned short*)(ws + 25198592);   // blocked bf16 (10 MB)
  unsigned short* wl  = (unsigned short*)(ws + 35684352);   // blocked bf16 (10 MB)

  hipMemsetAsync(var, 0, 6 * 1024 * sizeof(float), stream);
  convert_w<<<dim3(16, 16, 5), 256, 0, stream>>>(W, wh, wl);
  layer0_fused<<<dim3(4, 64), 256, 0, stream>>>(x, w1, pre, var);
  act_kernel<false><<<dim3(64, 8), 256, 0, stream>>>(pre, var, bnw, ah, al);
  for (int b = 0; b < 5; ++b) {
    gemm_fused<<<192, 512, 0, stream>>>(
        ah, al, (const char*)(wh + (size_t)b * PLANE), (const char*)(wl + (size_t)b * PLANE),
        pre, var + (b + 1) * 1024);
    act_kernel<true><<<dim3(64, 8), 256, 0, stream>>>(pre, var + (b + 1) * 1024,
                                                      bnw + (size_t)(b + 1) * 4096, ah, al);
  }
  final_kernel<<<1024, 256, 0, stream>>>(ah, al, wout, out);
}

// Round 13
// 208.526 us; speedup vs baseline: 1.0556x; 1.0556x over previous
//
#include <hip/hip_runtime.h>
#include <hip/hip_bf16.h>
#include <cstdint>
#include <cstddef>

// ---------------------------------------------------------------------------
// E3nnMLPNorm: only the l=1 (d=3) irrep path is nonzero.
// layer0(+colsumsq) -> [gemm(+colsumsq) -> bn+gate] x5 -> final dot
// Precision: bf16 hi+lo pairs, 3 bf16 MFMA per fragment into f32 acc.
// R11 = R9 structure (64x64 tile, 768 blocks = 3/CU TLP, depth-3 pipeline,
// K-blocked operands: 1KB-contiguous wave loads — the R9 1.7x win)
// + ONE change: fragment-blocked C stores (256B-contiguous per store) with
// act<true> reading the inverse layout. R10 confounded this with a tile
// change; this round isolates it.
// ---------------------------------------------------------------------------

typedef short    s16x8 __attribute__((ext_vector_type(8)));
typedef float    f32x4 __attribute__((ext_vector_type(4)));

#define PLANE 1048576   // 1024*1024 elements per plane

__device__ __forceinline__ unsigned short f2bf(float f) {
  unsigned u = __builtin_bit_cast(unsigned, f);
  u += 0x7FFFu + ((u >> 16) & 1u);              // round-to-nearest-even
  return (unsigned short)(u >> 16);
}
__device__ __forceinline__ float bf2f(unsigned short h) {
  return __builtin_bit_cast(float, (unsigned)h << 16);
}

// byte offset of element (row, k) in the K-blocked bf16 operand layout:
// [row>>6][k>>5][(row>>4)&3][(k>>3)&3][row&15][k&7]
__device__ __forceinline__ size_t ablk(int row, int k) {
  return ((size_t)(row >> 6) << 17) + ((size_t)(k >> 5) << 12)
       + ((size_t)((row >> 4) & 3) << 10) + ((size_t)((k >> 3) & 3) << 8)
       + ((size_t)(row & 15) << 4) + ((size_t)(k & 7) << 1);
}

// float index of C element (r,c) in the 64x64-tile fragment-blocked layout:
// tile (tM,tN) of 64x64; wave = (rr>>5)*2 + (cc>>5); within 32x32 quadrant:
// m=(rr>>4)&1, kc=(rr>>2)&3, j=rr&3, n=(cc>>4)&1, rs=cc&15; lane=kc*16+rs.
__device__ __forceinline__ size_t cblk64(int r, int c) {
  const int tM = r >> 6, tN = c >> 6;
  const int rr = r & 63, cc = c & 63;
  const int wave = ((rr >> 5) << 1) | (cc >> 5);
  const int m = (rr >> 4) & 1, kc = (rr >> 2) & 3, j = rr & 3;
  const int n = (cc >> 4) & 1, rs = cc & 15;
  return (((size_t)((tM * 16 + tN) * 4 + wave)) << 10)
       + (size_t)(((((m << 1) | n) << 2) | j) << 6) + (kc << 4) + rs;
}

__device__ __forceinline__ void load_lds16(const void* g, void* l) {
  __builtin_amdgcn_global_load_lds(
      (const __attribute__((address_space(1))) unsigned int*)g,
      (__attribute__((address_space(3))) unsigned int*)l,
      16, 0, 0);
}

// ---- W[b,0] (f32 [u][v]) -> blocked bf16 hi/lo (row=v, k=u), 1/32 folded ----
__global__ void convert_w(const float* __restrict__ W,
                          unsigned short* __restrict__ Wh,
                          unsigned short* __restrict__ Wl) {
  __shared__ float t[64][65];
  const int u0 = blockIdx.x * 64, v0 = blockIdx.y * 64;
  const float* Wb = W + (size_t)blockIdx.z * 4194304;   // [5][4][1024][1024], irrep 0
  char* Whb = (char*)(Wh + (size_t)blockIdx.z * PLANE);
  char* Wlb = (char*)(Wl + (size_t)blockIdx.z * PLANE);
  const int c = threadIdx.x & 63, r4 = threadIdx.x >> 6;
#pragma unroll
  for (int i = 0; i < 16; ++i) {
    const int r = i * 4 + r4;
    t[r][c] = Wb[(size_t)(u0 + r) * 1024 + v0 + c];
  }
  __syncthreads();
#pragma unroll
  for (int i = 0; i < 16; ++i) {
    const int r = i * 4 + r4;   // local v index
    const float w = t[c][r] * 0.03125f;      // exact pow2 scale
    const unsigned short hi = f2bf(w);
    const size_t off = ablk(v0 + r, u0 + c);
    *(unsigned short*)(Whb + off) = hi;
    *(unsigned short*)(Wlb + off) = f2bf(w - bf2f(hi));
  }
}

// ---- layer0 + fused colsumsq: pre[i][b][v] (linear f32), var[v] += sum f^2 --
__global__ void layer0_fused(const float* __restrict__ x, const float* __restrict__ w1,
                             float* __restrict__ pre, float* __restrict__ var) {
  const int v = blockIdx.x * 256 + threadIdx.x;
  const int b0 = blockIdx.y * 16;
  const float a0 = w1[v], a1 = w1[1024 + v];
  const float inv = 0.70710678118654752f;
  float ssq = 0.f;
#pragma unroll 4
  for (int bb = 0; bb < 16; ++bb) {
    const int b = b0 + bb;
    const float* xb = x + b * 6;                    // x flat [B][2][3]
#pragma unroll
    for (int i = 0; i < 3; ++i) {
      const float f = (xb[i] * a0 + xb[3 + i] * a1) * inv;
      pre[(size_t)i * PLANE + (size_t)b * 1024 + v] = f;
      ssq += f * f;
    }
  }
  atomicAdd(&var[v], ssq);
}

// ---- batchnorm + norm-gated sigmoid: C (linear or blocked) -> blocked hi/lo -
// block: 16 b x 128 v; thread: b = 16bx + (tid&15), v0 = 128by + (tid>>4)*8.
template <bool BLK>
__global__ void act_kernel(const float* __restrict__ Cin, const float* __restrict__ var,
                           const float* __restrict__ bnw,
                           char* __restrict__ ah, char* __restrict__ al) {
  const int tid = threadIdx.x;
  const int b  = blockIdx.x * 16 + (tid & 15);
  const int v0 = blockIdx.y * 128 + (tid >> 4) * 8;
  float s[8];
#pragma unroll
  for (int j = 0; j < 8; ++j)
    s[j] = bnw[v0 + j] / sqrtf(var[v0 + j] * (1.0f / 3072.0f) + 1e-5f);
  float f[3][8];
#pragma unroll
  for (int i = 0; i < 3; ++i) {
    float4 p0, p1;
    if (BLK) {
      const size_t ci = cblk64(i * 1024 + b, v0);   // 8 consecutive floats
      p0 = *(const float4*)&Cin[ci];
      p1 = *(const float4*)&Cin[ci + 4];
    } else {
      p0 = *(const float4*)&Cin[(size_t)i * PLANE + (size_t)b * 1024 + v0];
      p1 = *(const float4*)&Cin[(size_t)i * PLANE + (size_t)b * 1024 + v0 + 4];
    }
    f[i][0] = p0.x * s[0]; f[i][1] = p0.y * s[1]; f[i][2] = p0.z * s[2]; f[i][3] = p0.w * s[3];
    f[i][4] = p1.x * s[4]; f[i][5] = p1.y * s[5]; f[i][6] = p1.z * s[6]; f[i][7] = p1.w * s[7];
  }
#pragma unroll
  for (int j = 0; j < 8; ++j) {
    const float n = sqrtf(f[0][j] * f[0][j] + f[1][j] * f[1][j] + f[2][j] * f[2][j] + 1e-8f);
    const float g = 1.0f / ((1.0f + expf(-n)) * n);   // sigmoid(n)/n
    f[0][j] *= g; f[1][j] *= g; f[2][j] *= g;
  }
#pragma unroll
  for (int i = 0; i < 3; ++i) {
    s16x8 hi, lo;
#pragma unroll
    for (int j = 0; j < 8; ++j) {
      const unsigned short h = f2bf(f[i][j]);
      hi[j] = (short)h;
      lo[j] = (short)f2bf(f[i][j] - bf2f(h));
    }
    const size_t off = ablk(i * 1024 + b, v0);
    *(s16x8*)(ah + off) = hi;
    *(s16x8*)(al + off) = lo;
  }
}

// ---- bf16-pair MFMA GEMM + fused colsumsq, 64x64, depth-3, blocked I/O ------
// C(frag-blocked) = (Ah+Al)(Bh+Bl)^T ; var[col] += sum_rows C^2
__global__ __launch_bounds__(256, 3) void gemm_fused(
    const char* __restrict__ Ah, const char* __restrict__ Al,
    const char* __restrict__ Bh, const char* __restrict__ Bl,
    float* __restrict__ C, float* __restrict__ var) {
  // [buf 3][mat: aH,aL,bH,bL][w 4][kc 4][rl 16][8 halves] = 48 KB
  __shared__ unsigned short lds[3][4][4][4][16][8];
  const int tid = threadIdx.x;
  const int bid = blockIdx.x;
  const int xcd = bid & 7, q = bid >> 3;          // q in 0..95
  const int bm0 = (xcd * 6 + (q % 6)) * 64;
  const int bn0 = (q / 6) * 64;
  const int lane = tid & 63, wave = tid >> 6;
  const int wm = (wave >> 1) * 32, wn = (wave & 1) * 32;
  const int rsel = lane & 15, kcsel = lane >> 4;

  f32x4 acc[2][2] = {};

  // blocked staging bases: row-block (<<17) + wave (<<10) + lane (<<4);
  // each stage load reads 1KB CONTIGUOUS per wave.
  const size_t abase = ((size_t)(bm0 >> 6) << 17) + (wave << 10) + (lane << 4);
  const size_t bbase = ((size_t)(bn0 >> 6) << 17) + (wave << 10) + (lane << 4);
  const char* g0 = Ah + abase;
  const char* g1 = Al + abase;
  const char* g2 = Bh + bbase;
  const char* g3 = Bl + bbase;

  auto stage = [&](int buf, int t) {
    const size_t kb = (size_t)t << 12;               // 4KB per K-step block
    char* base = (char*)lds + buf * 16384 + (wave << 10);  // wave-uniform
    load_lds16(g0 + kb, base);
    load_lds16(g1 + kb, base + 4096);
    load_lds16(g2 + kb, base + 8192);
    load_lds16(g3 + kb, base + 12288);
  };

  // fragment offsets: mat*4096 + rowgrp*1024 + kcsel*256 + rsel*16 (bytes)
  const int fo = kcsel * 256 + rsel * 16;
  auto compute = [&](int buf) {
    const char* p = (const char*)lds + buf * 16384;
    s16x8 fah[2], fal[2], fbh[2], fbl[2];
#pragma unroll
    for (int m = 0; m < 2; ++m) {
      fah[m] = *(const s16x8*)(p         + ((wm >> 4) + m) * 1024 + fo);
      fal[m] = *(const s16x8*)(p + 4096  + ((wm >> 4) + m) * 1024 + fo);
    }
#pragma unroll
    for (int n = 0; n < 2; ++n) {
      fbh[n] = *(const s16x8*)(p + 8192  + ((wn >> 4) + n) * 1024 + fo);
      fbl[n] = *(const s16x8*)(p + 12288 + ((wn >> 4) + n) * 1024 + fo);
    }
#pragma unroll
    for (int m = 0; m < 2; ++m)
#pragma unroll
      for (int n = 0; n < 2; ++n) {
        acc[m][n] = __builtin_amdgcn_mfma_f32_16x16x32_bf16(fal[m], fbh[n], acc[m][n], 0, 0, 0);
        acc[m][n] = __builtin_amdgcn_mfma_f32_16x16x32_bf16(fah[m], fbl[n], acc[m][n], 0, 0, 0);
        acc[m][n] = __builtin_amdgcn_mfma_f32_16x16x32_bf16(fah[m], fbh[n], acc[m][n], 0, 0, 0);
      }
  };

  // prologue: fill 2 buffers ahead
  stage(0, 0);
  stage(1, 1);
  int cb = 0, sb = 2;                              // compute buf, stage buf
  for (int t = 0; t < 30; ++t) {
    stage(sb, t + 2);                              // issue 2 steps ahead
    __builtin_amdgcn_sched_barrier(0);
    asm volatile("s_waitcnt vmcnt(8)" ::: "memory");  // wait stage(t) only
    __builtin_amdgcn_sched_barrier(0);
    __builtin_amdgcn_s_barrier();
    compute(cb);
    __builtin_amdgcn_sched_barrier(0);
    __builtin_amdgcn_s_barrier();                  // protect buf before overwrite
    sb = cb;
    cb = (cb == 2) ? 0 : cb + 1;
  }
  // t=30: outstanding = stage(31)'s 4 loads
  asm volatile("s_waitcnt vmcnt(4)" ::: "memory");
  __builtin_amdgcn_sched_barrier(0);
  __builtin_amdgcn_s_barrier();
  compute(0);                                      // kt=30 lives in buf 0
  // t=31:
  asm volatile("s_waitcnt vmcnt(0)" ::: "memory");
  __builtin_amdgcn_sched_barrier(0);
  __builtin_amdgcn_s_barrier();
  compute(1);                                      // kt=31 lives in buf 1

  // epilogue: fragment-blocked C store (256B contiguous per store) + colsumsq
  float* cw = C + (((size_t)(((bm0 >> 6) * 16 + (bn0 >> 6)) * 4 + wave)) << 10) + lane;
  float csq[2] = {0.f, 0.f};
#pragma unroll
  for (int m = 0; m < 2; ++m)
#pragma unroll
    for (int n = 0; n < 2; ++n)
#pragma unroll
      for (int j = 0; j < 4; ++j) {
        const float v = acc[m][n][j];
        cw[((((m << 1) | n) << 2) | j) << 6] = v;
        csq[n] += v * v;
      }
  // reduce over kcsel (row groups): lanes rsel, +16, +32, +48
#pragma unroll
  for (int n = 0; n < 2; ++n) {
    csq[n] += __shfl_xor(csq[n], 16);
    csq[n] += __shfl_xor(csq[n], 32);
  }
  if (kcsel == 0) {
#pragma unroll
    for (int n = 0; n < 2; ++n)
      atomicAdd(&var[bn0 + wn + n * 16 + rsel], csq[n]);
  }
}

// ---- final: out[b,i] = (1/32) * sum_v act[i][b][v] * wout[v] ----------------
__global__ void final_kernel(const char* __restrict__ ah, const char* __restrict__ al,
                             const float* __restrict__ wout, float* __restrict__ out) {
  const int b = blockIdx.x, tid = threadIdx.x;
  __shared__ float red[3][4];
  float s[3] = {0.f, 0.f, 0.f};
  if (tid < 128) {
    const int v0 = tid * 8;
#pragma unroll
    for (int i = 0; i < 3; ++i) {
      const size_t off = ablk(i * 1024 + b, v0);
      const s16x8 hi = *(const s16x8*)(ah + off);
      const s16x8 lo = *(const s16x8*)(al + off);
#pragma unroll
      for (int j = 0; j < 8; ++j)
        s[i] += (bf2f((unsigned short)hi[j]) + bf2f((unsigned short)lo[j])) * wout[v0 + j];
    }
  }
#pragma unroll
  for (int i = 0; i < 3; ++i)
    for (int o = 32; o >= 1; o >>= 1) s[i] += __shfl_down(s[i], o);
  if ((tid & 63) == 0)
#pragma unroll
    for (int i = 0; i < 3; ++i) red[i][tid >> 6] = s[i];
  __syncthreads();
  if (tid < 3) {
    const float t = red[tid][0] + red[tid][1] + red[tid][2] + red[tid][3];
    out[b * 3 + tid] = t * 0.03125f;
  }
}

extern "C" void kernel_launch(void* const* d_in, const int* in_sizes, int n_in,
                              void* d_out, int out_size, void* d_ws, size_t ws_size,
                              hipStream_t stream) {
  const float* x    = (const float*)d_in[0];
  const float* w1   = (const float*)d_in[1];
  const float* W    = (const float*)d_in[2];
  const float* bnw  = (const float*)d_in[3];
  const float* wout = (const float*)d_in[4];
  float* out = (float*)d_out;

  char* ws = (char*)d_ws;
  float*          var = (float*)ws;                         // 6*1024 f32 (32 KB resv)
  float*          pre = (float*)(ws + 32768);               // C buffer, 12 MB
  char*           ah  = ws + 12615680;                      // blocked bf16 (6 MB)
  char*           al  = ws + 18907136;                      // blocked bf16 (6 MB)
  unsigned short* wh  = (unsigned short*)(ws + 25198592);   // blocked bf16 (10 MB)
  unsigned short* wl  = (unsigned short*)(ws + 35684352);   // blocked bf16 (10 MB)

  hipMemsetAsync(var, 0, 6 * 1024 * sizeof(float), stream);
  convert_w<<<dim3(16, 16, 5), 256, 0, stream>>>(W, wh, wl);
  layer0_fused<<<dim3(4, 64), 256, 0, stream>>>(x, w1, pre, var);
  act_kernel<false><<<dim3(64, 8), 256, 0, stream>>>(pre, var, bnw, ah, al);
  for (int b = 0; b < 5; ++b) {
    gemm_fused<<<768, 256, 0, stream>>>(
        ah, al, (const char*)(wh + (size_t)b * PLANE), (const char*)(wl + (size_t)b * PLANE),
        pre, var + (b + 1) * 1024);
    act_kernel<true><<<dim3(64, 8), 256, 0, stream>>>(pre, var + (b + 1) * 1024,
                                                      bnw + (size_t)(b + 1) * 4096, ah, al);
  }
  final_kernel<<<1024, 256, 0, stream>>>(ah, al, wout, out);
}

// Round 15
// 205.825 us; speedup vs baseline: 1.0694x; 1.0131x over previous
//
#include <hip/hip_runtime.h>
#include <hip/hip_bf16.h>
#include <cstdint>
#include <cstddef>

// ---------------------------------------------------------------------------
// E3nnMLPNorm: only the l=1 (d=3) irrep path is nonzero.
// layer0(+colsumsq) -> [gemm(+colsumsq) -> bn+gate] x5 -> final dot
// Precision: bf16 hi+lo pairs, 3 bf16 MFMA per fragment into f32 acc.
// R14: DIRECT-TO-REGISTER GEMM. The K-blocked layout (R9) is exactly MFMA
// fragment order, so waves load fragments global->VGPR (dwordx4), skipping
// LDS entirely (R9-R13 analysis: LDS round-trip = 4.5 MB/CU at ~60 B/cy was
// the binding pipe; L2 link ran at 1/3 capacity). 768 one-wave blocks,
// 64x64 tile/wave, reg double-buffer, no barriers, no LDS.
// ---------------------------------------------------------------------------

typedef short    s16x8 __attribute__((ext_vector_type(8)));
typedef float    f32x4 __attribute__((ext_vector_type(4)));

#define PLANE 1048576   // 1024*1024 elements per plane

__device__ __forceinline__ unsigned short f2bf(float f) {
  unsigned u = __builtin_bit_cast(unsigned, f);
  u += 0x7FFFu + ((u >> 16) & 1u);              // round-to-nearest-even
  return (unsigned short)(u >> 16);
}
__device__ __forceinline__ float bf2f(unsigned short h) {
  return __builtin_bit_cast(float, (unsigned)h << 16);
}

// byte offset of element (row, k) in the K-blocked bf16 operand layout:
// [row>>6][k>>5][(row>>4)&3][(k>>3)&3][row&15][k&7]
__device__ __forceinline__ size_t ablk(int row, int k) {
  return ((size_t)(row >> 6) << 17) + ((size_t)(k >> 5) << 12)
       + ((size_t)((row >> 4) & 3) << 10) + ((size_t)((k >> 3) & 3) << 8)
       + ((size_t)(row & 15) << 4) + ((size_t)(k & 7) << 1);
}

// ---- W[b,0] (f32 [u][v]) -> blocked bf16 hi/lo (row=v, k=u), 1/32 folded ----
__global__ void convert_w(const float* __restrict__ W,
                          unsigned short* __restrict__ Wh,
                          unsigned short* __restrict__ Wl) {
  __shared__ float t[64][65];
  const int u0 = blockIdx.x * 64, v0 = blockIdx.y * 64;
  const float* Wb = W + (size_t)blockIdx.z * 4194304;   // [5][4][1024][1024], irrep 0
  char* Whb = (char*)(Wh + (size_t)blockIdx.z * PLANE);
  char* Wlb = (char*)(Wl + (size_t)blockIdx.z * PLANE);
  const int c = threadIdx.x & 63, r4 = threadIdx.x >> 6;
#pragma unroll
  for (int i = 0; i < 16; ++i) {
    const int r = i * 4 + r4;
    t[r][c] = Wb[(size_t)(u0 + r) * 1024 + v0 + c];
  }
  __syncthreads();
#pragma unroll
  for (int i = 0; i < 16; ++i) {
    const int r = i * 4 + r4;   // local v index
    const float w = t[c][r] * 0.03125f;      // exact pow2 scale
    const unsigned short hi = f2bf(w);
    const size_t off = ablk(v0 + r, u0 + c);
    *(unsigned short*)(Whb + off) = hi;
    *(unsigned short*)(Wlb + off) = f2bf(w - bf2f(hi));
  }
}

// ---- layer0 + fused colsumsq: pre[i][b][v] (linear f32), var[v] += sum f^2 --
__global__ void layer0_fused(const float* __restrict__ x, const float* __restrict__ w1,
                             float* __restrict__ pre, float* __restrict__ var) {
  const int v = blockIdx.x * 256 + threadIdx.x;
  const int b0 = blockIdx.y * 16;
  const float a0 = w1[v], a1 = w1[1024 + v];
  const float inv = 0.70710678118654752f;
  float ssq = 0.f;
#pragma unroll 4
  for (int bb = 0; bb < 16; ++bb) {
    const int b = b0 + bb;
    const float* xb = x + b * 6;                    // x flat [B][2][3]
#pragma unroll
    for (int i = 0; i < 3; ++i) {
      const float f = (xb[i] * a0 + xb[3 + i] * a1) * inv;
      pre[(size_t)i * PLANE + (size_t)b * 1024 + v] = f;
      ssq += f * f;
    }
  }
  atomicAdd(&var[v], ssq);
}

// ---- batchnorm + norm-gated sigmoid: pre (linear f32) -> blocked bf16 hi/lo -
// block: 16 b x 128 v; thread: b = 16bx + (tid&15), v0 = 128by + (tid>>4)*8.
__global__ void act_kernel(const float* __restrict__ pre, const float* __restrict__ var,
                           const float* __restrict__ bnw,
                           char* __restrict__ ah, char* __restrict__ al) {
  const int tid = threadIdx.x;
  const int b  = blockIdx.x * 16 + (tid & 15);
  const int v0 = blockIdx.y * 128 + (tid >> 4) * 8;
  float s[8];
#pragma unroll
  for (int j = 0; j < 8; ++j)
    s[j] = bnw[v0 + j] / sqrtf(var[v0 + j] * (1.0f / 3072.0f) + 1e-5f);
  float f[3][8];
#pragma unroll
  for (int i = 0; i < 3; ++i) {
    const float4 p0 = *(const float4*)&pre[(size_t)i * PLANE + (size_t)b * 1024 + v0];
    const float4 p1 = *(const float4*)&pre[(size_t)i * PLANE + (size_t)b * 1024 + v0 + 4];
    f[i][0] = p0.x * s[0]; f[i][1] = p0.y * s[1]; f[i][2] = p0.z * s[2]; f[i][3] = p0.w * s[3];
    f[i][4] = p1.x * s[4]; f[i][5] = p1.y * s[5]; f[i][6] = p1.z * s[6]; f[i][7] = p1.w * s[7];
  }
#pragma unroll
  for (int j = 0; j < 8; ++j) {
    const float n = sqrtf(f[0][j] * f[0][j] + f[1][j] * f[1][j] + f[2][j] * f[2][j] + 1e-8f);
    const float g = 1.0f / ((1.0f + expf(-n)) * n);   // sigmoid(n)/n
    f[0][j] *= g; f[1][j] *= g; f[2][j] *= g;
  }
#pragma unroll
  for (int i = 0; i < 3; ++i) {
    s16x8 hi, lo;
#pragma unroll
    for (int j = 0; j < 8; ++j) {
      const unsigned short h = f2bf(f[i][j]);
      hi[j] = (short)h;
      lo[j] = (short)f2bf(f[i][j] - bf2f(h));
    }
    const size_t off = ablk(i * 1024 + b, v0);
    *(s16x8*)(ah + off) = hi;
    *(s16x8*)(al + off) = lo;
  }
}

// ---- direct-to-register bf16-pair MFMA GEMM + fused colsumsq ----------------
// One wave per block; wave owns a 64x64 tile (4x4 frags of 16x16x32).
// Fragments loaded global->VGPR (blocked layout IS fragment order). No LDS.
#define LOADF(A_, B_, t_)                                                      \
  {                                                                            \
    const size_t kb_ = (size_t)(t_) << 12;                                     \
    _Pragma("unroll")                                                          \
    for (int m_ = 0; m_ < 4; ++m_) {                                           \
      A_[m_]     = *(const s16x8*)(a_h + kb_ + (m_ << 10));                    \
      A_[4 + m_] = *(const s16x8*)(a_l + kb_ + (m_ << 10));                    \
      B_[m_]     = *(const s16x8*)(b_h + kb_ + (m_ << 10));                    \
      B_[4 + m_] = *(const s16x8*)(b_l + kb_ + (m_ << 10));                    \
    }                                                                          \
  }
#define COMPUTEF(A_, B_)                                                       \
  {                                                                            \
    _Pragma("unroll")                                                          \
    for (int m_ = 0; m_ < 4; ++m_)                                             \
      _Pragma("unroll")                                                        \
      for (int n_ = 0; n_ < 4; ++n_) {                                         \
        acc[m_][n_] = __builtin_amdgcn_mfma_f32_16x16x32_bf16(                 \
            A_[4 + m_], B_[n_], acc[m_][n_], 0, 0, 0);                         \
        acc[m_][n_] = __builtin_amdgcn_mfma_f32_16x16x32_bf16(                 \
            A_[m_], B_[4 + n_], acc[m_][n_], 0, 0, 0);                         \
        acc[m_][n_] = __builtin_amdgcn_mfma_f32_16x16x32_bf16(                 \
            A_[m_], B_[n_], acc[m_][n_], 0, 0, 0);                             \
      }                                                                        \
  }

__global__ __launch_bounds__(64, 2) void gemm_reg(
    const char* __restrict__ Ah, const char* __restrict__ Al,
    const char* __restrict__ Bh, const char* __restrict__ Bl,
    float* __restrict__ C, float* __restrict__ var) {
  const int bid = blockIdx.x;
  const int xcd = bid & 7, q = bid >> 3;          // q in 0..95
  const int tm = xcd * 6 + (q % 6);               // 0..47 (XCD M-stripe)
  const int tn = q / 6;                           // 0..15
  const int lane = threadIdx.x;
  const int rsel = lane & 15, kcsel = lane >> 4;

  // fragment base pointers: rowgroup m of the tile's 64-row block, step t:
  // base + (t<<12) + (m<<10) + lane*16  — 16B/lane, wave-contiguous 1KB.
  const size_t la = (size_t)lane << 4;
  const char* a_h = Ah + ((size_t)tm << 17) + la;
  const char* a_l = Al + ((size_t)tm << 17) + la;
  const char* b_h = Bh + ((size_t)tn << 17) + la;
  const char* b_l = Bl + ((size_t)tn << 17) + la;

  f32x4 acc[4][4] = {};
  s16x8 A0[8], B0[8], A1[8], B1[8];

  LOADF(A0, B0, 0);
  LOADF(A1, B1, 1);
  for (int t = 0; t < 30; t += 2) {
    COMPUTEF(A0, B0);            // step t
    LOADF(A0, B0, t + 2);
    COMPUTEF(A1, B1);            // step t+1
    LOADF(A1, B1, t + 3);        // last iteration loads step 31
  }
  COMPUTEF(A0, B0);              // step 30
  COMPUTEF(A1, B1);              // step 31

  // epilogue: linear C store + fused per-column sum of squares
  // frag (m,n) elem j: row = tm*64 + m*16 + kcsel*4 + j, col = tn*64 + n*16 + rsel
  const int r0 = tm * 64 + (kcsel << 2);
  const int c0 = tn * 64 + rsel;
  float csq[4] = {0.f, 0.f, 0.f, 0.f};
#pragma unroll
  for (int m = 0; m < 4; ++m)
#pragma unroll
    for (int n = 0; n < 4; ++n)
#pragma unroll
      for (int j = 0; j < 4; ++j) {
        const float v = acc[m][n][j];
        C[(size_t)(r0 + m * 16 + j) * 1024 + c0 + n * 16] = v;
        csq[n] += v * v;
      }
#pragma unroll
  for (int n = 0; n < 4; ++n) {
    csq[n] += __shfl_xor(csq[n], 16);
    csq[n] += __shfl_xor(csq[n], 32);
  }
  if (kcsel == 0) {
#pragma unroll
    for (int n = 0; n < 4; ++n)
      atomicAdd(&var[c0 + n * 16], csq[n]);
  }
}

// ---- final: out[b,i] = (1/32) * sum_v act[i][b][v] * wout[v] ----------------
__global__ void final_kernel(const char* __restrict__ ah, const char* __restrict__ al,
                             const float* __restrict__ wout, float* __restrict__ out) {
  const int b = blockIdx.x, tid = threadIdx.x;
  __shared__ float red[3][4];
  float s[3] = {0.f, 0.f, 0.f};
  if (tid < 128) {
    const int v0 = tid * 8;
#pragma unroll
    for (int i = 0; i < 3; ++i) {
      const size_t off = ablk(i * 1024 + b, v0);
      const s16x8 hi = *(const s16x8*)(ah + off);
      const s16x8 lo = *(const s16x8*)(al + off);
#pragma unroll
      for (int j = 0; j < 8; ++j)
        s[i] += (bf2f((unsigned short)hi[j]) + bf2f((unsigned short)lo[j])) * wout[v0 + j];
    }
  }
#pragma unroll
  for (int i = 0; i < 3; ++i)
    for (int o = 32; o >= 1; o >>= 1) s[i] += __shfl_down(s[i], o);
  if ((tid & 63) == 0)
#pragma unroll
    for (int i = 0; i < 3; ++i) red[i][tid >> 6] = s[i];
  __syncthreads();
  if (tid < 3) {
    const float t = red[tid][0] + red[tid][1] + red[tid][2] + red[tid][3];
    out[b * 3 + tid] = t * 0.03125f;
  }
}

extern "C" void kernel_launch(void* const* d_in, const int* in_sizes, int n_in,
                              void* d_out, int out_size, void* d_ws, size_t ws_size,
                              hipStream_t stream) {
  const float* x    = (const float*)d_in[0];
  const float* w1   = (const float*)d_in[1];
  const float* W    = (const float*)d_in[2];
  const float* bnw  = (const float*)d_in[3];
  const float* wout = (const float*)d_in[4];
  float* out = (float*)d_out;

  char* ws = (char*)d_ws;
  float*          var = (float*)ws;                         // 6*1024 f32 (32 KB resv)
  float*          pre = (float*)(ws + 32768);               // C buffer, 12 MB
  char*           ah  = ws + 12615680;                      // blocked bf16 (6 MB)
  char*           al  = ws + 18907136;                      // blocked bf16 (6 MB)
  unsigned short* wh  = (unsigned short*)(ws + 25198592);   // blocked bf16 (10 MB)
  unsigned short* wl  = (unsigned short*)(ws + 35684352);   // blocked bf16 (10 MB)

  hipMemsetAsync(var, 0, 6 * 1024 * sizeof(float), stream);
  convert_w<<<dim3(16, 16, 5), 256, 0, stream>>>(W, wh, wl);
  layer0_fused<<<dim3(4, 64), 256, 0, stream>>>(x, w1, pre, var);
  act_kernel<<<dim3(64, 8), 256, 0, stream>>>(pre, var, bnw, ah, al);
  for (int b = 0; b < 5; ++b) {
    gemm_reg<<<768, 64, 0, stream>>>(
        ah, al, (const char*)(wh + (size_t)b * PLANE), (const char*)(wl + (size_t)b * PLANE),
        pre, var + (b + 1) * 1024);
    act_kernel<<<dim3(64, 8), 256, 0, stream>>>(pre, var + (b + 1) * 1024,
                                                bnw + (size_t)(b + 1) * 4096, ah, al);
  }
  final_kernel<<<1024, 256, 0, stream>>>(ah, al, wout, out);
}